// Round 7
// baseline (216.433 us; speedup 1.0000x reference)
//
#include <hip/hip_runtime.h>
#include <math.h>

#define N_TOK 4096
#define NH    4

typedef __attribute__((ext_vector_type(8))) short bf16x8;
typedef __attribute__((ext_vector_type(4))) short bf16x4;
typedef __attribute__((ext_vector_type(4))) float f32x4;

static constexpr float SCALE   = 0.17677669529663687f; // 32^-0.5
static constexpr float LAMBDA_ = 0.1f;

__device__ __forceinline__ unsigned short bf_rne(float f) {
    unsigned u = __float_as_uint(f);
    u += 0x7FFF + ((u >> 16) & 1);
    return (unsigned short)(u >> 16);
}

// ---------------------------------------------------------------------------
// Kernel 1: qkv projection + operand packing.
//  qA[h][n][64] bf16: {q1hi(16) q1lo(16) q2hi(16) q2lo(16)}  (scale folded)
//  kB[h][n][64] bf16: {k1hi(16) k1lo(16) k2hi(16) k2lo(16)}
//  vT[h][32][4096] bf16 (transposed, RNE)
// Compute loop: w staged through LDS in 16-ch chunks, coalesced b128 loads.
// NEW epilogue: results repacked via LDS, written as 16B/8B vector stores
// (128 stores/block) instead of ~2.5k scattered 2B stores.
// ---------------------------------------------------------------------------
__global__ __launch_bounds__(128) void qkv_kernel(
    const float* __restrict__ x, const float* __restrict__ w,
    unsigned short* __restrict__ qA, unsigned short* __restrict__ kB,
    unsigned short* __restrict__ vT)
{
    __shared__ __align__(16) float xst[4][132];   // [token][channel]
    __shared__ __align__(16) float w_sh[384][18]; // 16-ch chunk of w, padded
    __shared__ __align__(16) unsigned short qsh[4][4][64]; // [h][tok][record]
    __shared__ __align__(16) unsigned short ksh[4][4][64];
    __shared__ __align__(8)  unsigned short vsh[4][32][4];  // [h][d][tok]
    const int t  = threadIdx.x;
    const int n0 = blockIdx.x * 4;

    #pragma unroll
    for (int i = 0; i < 4; ++i) {
        int n  = n0 + i;
        int nh = n >> 8, nw = (n >> 4) & 15, nz = n & 15;
        xst[i][t] = x[t * 32768 + nh * 2048 + nw * 64 + nz * 2];
    }

    float acc[3][4];
    #pragma unroll
    for (int oi = 0; oi < 3; ++oi)
        #pragma unroll
        for (int i = 0; i < 4; ++i) acc[oi][i] = 0.f;

    for (int chunk = 0; chunk < 8; ++chunk) {
        const int k0 = chunk * 16;
        __syncthreads();                      // prev compute done (and xst ready)
        #pragma unroll
        for (int i = 0; i < 12; ++i) {
            int idx = t + i * 128;            // 0..1535
            int row = idx >> 2, c4 = idx & 3;
            float4 wv = *(const float4*)(w + (size_t)row * 128 + k0 + c4 * 4);
            *(float2*)&w_sh[row][c4 * 4]     = make_float2(wv.x, wv.y);
            *(float2*)&w_sh[row][c4 * 4 + 2] = make_float2(wv.z, wv.w);
        }
        __syncthreads();
        #pragma unroll
        for (int c4 = 0; c4 < 4; ++c4) {
            float4 xv[4];
            #pragma unroll
            for (int i = 0; i < 4; ++i)
                xv[i] = *(const float4*)&xst[i][k0 + c4 * 4];
            float2 wa0 = *(const float2*)&w_sh[t][c4 * 4];
            float2 wb0 = *(const float2*)&w_sh[t][c4 * 4 + 2];
            float2 wa1 = *(const float2*)&w_sh[t + 128][c4 * 4];
            float2 wb1 = *(const float2*)&w_sh[t + 128][c4 * 4 + 2];
            float2 wa2 = *(const float2*)&w_sh[t + 256][c4 * 4];
            float2 wb2 = *(const float2*)&w_sh[t + 256][c4 * 4 + 2];
            #pragma unroll
            for (int i = 0; i < 4; ++i) {
                acc[0][i] += wa0.x*xv[i].x + wa0.y*xv[i].y + wb0.x*xv[i].z + wb0.y*xv[i].w;
                acc[1][i] += wa1.x*xv[i].x + wa1.y*xv[i].y + wb1.x*xv[i].z + wb1.y*xv[i].w;
                acc[2][i] += wa2.x*xv[i].x + wa2.y*xv[i].y + wb2.x*xv[i].z + wb2.y*xv[i].w;
            }
        }
    }

    // ---- epilogue: pack into LDS, then vectorized global stores ----
    #pragma unroll
    for (int oi = 0; oi < 3; ++oi) {
        int o  = t + oi * 128;                // 0..383
        int hh = o / 96;
        int r  = o - hh * 96;
        if (r < 64) {                         // q (r<32) or k (32..63)
            int rr = r & 31, part = rr >> 4, d = rr & 15;
            float sc = (r < 32) ? SCALE : 1.0f;
            #pragma unroll
            for (int i = 0; i < 4; ++i) {
                float f = acc[oi][i] * sc;
                unsigned u  = __float_as_uint(f);
                float lo = f - __uint_as_float(u & 0xFFFF0000u);
                unsigned short hi16 = (unsigned short)(u >> 16);
                unsigned short lo16 = (unsigned short)(__float_as_uint(lo) >> 16);
                if (r < 32) {
                    qsh[hh][i][part * 32 + d]      = hi16;
                    qsh[hh][i][part * 32 + d + 16] = lo16;
                } else {
                    ksh[hh][i][part * 32 + d]      = hi16;
                    ksh[hh][i][part * 32 + d + 16] = lo16;
                }
            }
        } else {
            int d = r - 64;
            #pragma unroll
            for (int i = 0; i < 4; ++i)
                vsh[hh][d][i] = bf_rne(acc[oi][i]);
        }
    }
    __syncthreads();
    {   // qA/kB: 16 records x 8 chunks of 16B, one uint4 store per thread each
        int rec = t >> 3, ch = t & 7;
        int hh  = rec >> 2, i = rec & 3;
        size_t base = ((size_t)hh * N_TOK + n0 + i) * 64 + ch * 8;
        *(uint4*)(qA + base) = *(const uint4*)&qsh[hh][i][ch * 8];
        *(uint4*)(kB + base) = *(const uint4*)&ksh[hh][i][ch * 8];
    }
    {   // vT: 128 rows x one 8B store (4 consecutive tokens)
        int hh = t >> 5, d = t & 31;
        *(ushort4*)(vT + ((size_t)hh * 32 + d) * N_TOK + n0) =
            *(const ushort4*)&vsh[hh][d][0];
    }
}

// ---------------------------------------------------------------------------
// Kernel 2: MFMA flash diff-attention v4 — barrier-free K-loop.
// block = 16 queries x 4096 keys, 4 waves; wave w owns keys [w*1024,(w+1)*1024)
// in 64 slices of 16 keys. All fragments loaded straight from global into
// VGPRs through an explicit depth-4 rotating register pipeline (loads for
// slice s+4 issued before computing slice s => fine-grained vmcnt, no
// barriers, no LDS in the loop).
// In-register S^T->PV trick (R5-verified): S^T = K.Q^T via 16x16x32
// (A=K hi|lo, B=Q); C-layout == A-layout of 16x16x16bf16_1k PV.
// Merge 4 wave-partials via LDS atomics; fused finalize.
// ---------------------------------------------------------------------------
__global__ __launch_bounds__(256, 4) void flash_kernel(
    const unsigned short* __restrict__ qA, const unsigned short* __restrict__ kB,
    const unsigned short* __restrict__ vT, float* __restrict__ out)
{
    __shared__ float Obuf[2][16][32];
    __shared__ float lbuf[2][16];

    const int t    = threadIdx.x;
    const int w    = t >> 6;
    const int lane = t & 63;
    const int m    = lane & 15;
    const int quad = lane >> 4;
    const int h     = blockIdx.x >> 8;
    const int qbase = (blockIdx.x & 255) * 16;

    for (int i = t; i < 1024; i += 256) ((float*)Obuf)[i] = 0.f;
    if (t < 32) ((float*)lbuf)[t] = 0.f;
    __syncthreads();

    // B-operand query fragments (R5-verified construction)
    const unsigned short* qrec = qA + (size_t)(h * N_TOK + qbase + m) * 64;
    const bf16x8 zz = {0,0,0,0,0,0,0,0};
    bf16x8 Bq1h = *(const bf16x8*)(qrec + (quad & 1) * 8);
    bf16x8 Bq2h = *(const bf16x8*)(qrec + 32 + (quad & 1) * 8);
    bf16x8 Bq1l = (quad < 2) ? *(const bf16x8*)(qrec + 16 + quad * 8) : zz;
    bf16x8 Bq2l = (quad < 2) ? *(const bf16x8*)(qrec + 48 + quad * 8) : zz;

    f32x4 O1a = {0,0,0,0}, O1b = {0,0,0,0}, O2a = {0,0,0,0}, O2b = {0,0,0,0};
    float l1 = 0.f, l2 = 0.f;

    // per-wave global fragment bases (R5-verified addressing)
    const unsigned short* kb0 = kB + (size_t)h * N_TOK * 64
                                   + (size_t)(w * 1024 + m) * 64;
    const unsigned short* vt0 = vT + (size_t)h * 32 * N_TOK
                                   + (size_t)m * N_TOK + w * 1024 + quad * 4;
    const unsigned short* vt1 = vt0 + 16 * N_TOK;

    // depth-4 rotating register pipeline
    bf16x8 K1[4], K2[4];
    bf16x4 V0[4], V1[4];
    #pragma unroll
    for (int i = 0; i < 4; ++i) {
        K1[i] = *(const bf16x8*)(kb0 + i * 1024 + quad * 8);
        K2[i] = *(const bf16x8*)(kb0 + i * 1024 + 32 + quad * 8);
        V0[i] = *(const bf16x4*)(vt0 + i * 16);
        V1[i] = *(const bf16x4*)(vt1 + i * 16);
    }

    #pragma unroll 4
    for (int s = 0; s < 64; ++s) {
        const int slot = s & 3;
        bf16x8 Ak1 = K1[slot], Ak2 = K2[slot];
        bf16x4 Vb0 = V0[slot], Vb1 = V1[slot];
        const int nx = (s + 4) & 63;          // wraps at tail (harmless reload)
        K1[slot] = *(const bf16x8*)(kb0 + nx * 1024 + quad * 8);
        K2[slot] = *(const bf16x8*)(kb0 + nx * 1024 + 32 + quad * 8);
        V0[slot] = *(const bf16x4*)(vt0 + nx * 16);
        V1[slot] = *(const bf16x4*)(vt1 + nx * 16);

        f32x4 s1 = {0,0,0,0}, s2 = {0,0,0,0};
        s1 = __builtin_amdgcn_mfma_f32_16x16x32_bf16(Ak1, Bq1h, s1, 0, 0, 0);
        s1 = __builtin_amdgcn_mfma_f32_16x16x32_bf16(Ak1, Bq1l, s1, 0, 0, 0);
        s2 = __builtin_amdgcn_mfma_f32_16x16x32_bf16(Ak2, Bq2h, s2, 0, 0, 0);
        s2 = __builtin_amdgcn_mfma_f32_16x16x32_bf16(Ak2, Bq2l, s2, 0, 0, 0);

        bf16x4 aP1, aP2;
        #pragma unroll
        for (int i = 0; i < 4; ++i) {
            float p1 = __expf(s1[i]);
            float p2 = __expf(s2[i]);
            l1 += p1; l2 += p2;
            aP1[i] = (short)(__float_as_uint(p1) >> 16);
            aP2[i] = (short)(__float_as_uint(p2) >> 16);
        }

        O1a = __builtin_amdgcn_mfma_f32_16x16x16bf16_1k(aP1, Vb0, O1a, 0, 0, 0);
        O1b = __builtin_amdgcn_mfma_f32_16x16x16bf16_1k(aP1, Vb1, O1b, 0, 0, 0);
        O2a = __builtin_amdgcn_mfma_f32_16x16x16bf16_1k(aP2, Vb0, O2a, 0, 0, 0);
        O2b = __builtin_amdgcn_mfma_f32_16x16x16bf16_1k(aP2, Vb1, O2b, 0, 0, 0);
    }

    // reduce l across quads (each lane covers keys {quad*4+i} of query m)
    l1 += __shfl_xor(l1, 16, 64); l1 += __shfl_xor(l1, 32, 64);
    l2 += __shfl_xor(l2, 16, 64); l2 += __shfl_xor(l2, 32, 64);
    if (lane < 16) {
        atomicAdd(&lbuf[0][m], l1);
        atomicAdd(&lbuf[1][m], l2);
    }
    #pragma unroll
    for (int i = 0; i < 4; ++i) {
        int r = quad * 4 + i;              // query row
        atomicAdd(&Obuf[0][r][m],      O1a[i]);
        atomicAdd(&Obuf[0][r][16 + m], O1b[i]);
        atomicAdd(&Obuf[1][r][m],      O2a[i]);
        atomicAdd(&Obuf[1][r][16 + m], O2b[i]);
    }
    __syncthreads();

    if (w == 0) {
        #pragma unroll
        for (int i = 0; i < 4; ++i) {
            int r = quad * 4 + i;
            float il1 = 1.0f    / lbuf[0][r];
            float il2 = LAMBDA_ / lbuf[1][r];
            float* op = out + ((size_t)(h * N_TOK + qbase + r)) * 32;
            op[m]      = Obuf[0][r][m]      * il1 - Obuf[1][r][m]      * il2;
            op[16 + m] = Obuf[0][r][16 + m] * il1 - Obuf[1][r][16 + m] * il2;
        }
    }
}

extern "C" void kernel_launch(void* const* d_in, const int* in_sizes, int n_in,
                              void* d_out, int out_size, void* d_ws, size_t ws_size,
                              hipStream_t stream) {
    const float* x = (const float*)d_in[0];   // (1,128,32,32,32)
    const float* w = (const float*)d_in[1];   // (384,128)
    float* out = (float*)d_out;               // [h][n][32] flat (verified R1)

    unsigned short* qA = (unsigned short*)d_ws;               // 2 MB
    unsigned short* kB = qA + (size_t)NH * N_TOK * 64;        // 2 MB
    unsigned short* vT = kB + (size_t)NH * N_TOK * 64;        // 1 MB

    qkv_kernel<<<1024, 128, 0, stream>>>(x, w, qA, kB, vT);
    flash_kernel<<<1024, 256, 0, stream>>>(qA, kB, vT, out);
}

// Round 8
// 154.037 us; speedup vs baseline: 1.4051x; 1.4051x over previous
//
#include <hip/hip_runtime.h>
#include <math.h>

#define N_TOK 4096
#define NH    4

typedef __attribute__((ext_vector_type(8))) short bf16x8;
typedef __attribute__((ext_vector_type(4))) short bf16x4;
typedef __attribute__((ext_vector_type(4))) float f32x4;

static constexpr float SCALE   = 0.17677669529663687f; // 32^-0.5
static constexpr float LAMBDA_ = 0.1f;

__device__ __forceinline__ unsigned short bf_rne(float f) {
    unsigned u = __float_as_uint(f);
    u += 0x7FFF + ((u >> 16) & 1);
    return (unsigned short)(u >> 16);
}

__device__ __forceinline__ void async_copy16(const unsigned short* g, unsigned short* l) {
    __builtin_amdgcn_global_load_lds(
        (const __attribute__((address_space(1))) void*)g,
        (__attribute__((address_space(3))) void*)l, 16, 0, 0);
}

// ---------------------------------------------------------------------------
// Kernel 1: qkv projection + operand packing, v3.
// 256 blocks x 512 thr, 16 tokens/block: w read ONCE per block (4x less L2
// traffic than before), x gathered token-major (consecutive lanes=consecutive
// tokens, 8B stride), 8 w-chunks of 16 ch staged in LDS, vector-packed stores.
//  qA[h][n][64] bf16: {q1hi(16) q1lo(16) q2hi(16) q2lo(16)}  (scale folded)
//  kB[h][n][64] bf16: {k1hi(16) k1lo(16) k2hi(16) k2lo(16)}
//  vT[h][32][4096] bf16 (transposed, RNE)
// ---------------------------------------------------------------------------
__global__ __launch_bounds__(512) void qkv_kernel(
    const float* __restrict__ x, const float* __restrict__ w,
    unsigned short* __restrict__ qA, unsigned short* __restrict__ kB,
    unsigned short* __restrict__ vT)
{
    __shared__ __align__(16) float w_sh[384][18];          // 27.6 KB
    __shared__ __align__(16) float xst[16][132];           // 8.4 KB [tok][ch]
    __shared__ __align__(16) unsigned short qsh[4][16][64];// 8 KB [h][tok][rec]
    __shared__ __align__(16) unsigned short ksh[4][16][64];// 8 KB
    __shared__ __align__(16) unsigned short vsh[4][32][16];// 4 KB [h][d][tok]

    const int t  = threadIdx.x;
    const int n0 = blockIdx.x * 16;            // 16 tokens, same nh/nw, nz=tok
    const int nh = n0 >> 8, nw = (n0 >> 4) & 15;
    const int xbase = nh * 2048 + nw * 64;

    // stage x: 2048 floats; lane-major over tokens -> 8B stride, coalesced
    #pragma unroll
    for (int k = 0; k < 4; ++k) {
        int idx = t + k * 512;                 // 0..2047
        int tok = idx & 15, ch = idx >> 4;
        xst[tok][ch] = x[(size_t)ch * 32768 + xbase + tok * 2];
    }

    float acc[3][4];
    #pragma unroll
    for (int k = 0; k < 3; ++k)
        #pragma unroll
        for (int j = 0; j < 4; ++j) acc[k][j] = 0.f;

    for (int chunk = 0; chunk < 8; ++chunk) {
        __syncthreads();                       // xst ready / prev compute done
        // stage w[:, chunk*16 .. +16]: 1536 float4 / 512 thr = 3 each
        #pragma unroll
        for (int k = 0; k < 3; ++k) {
            int idx = t + k * 512;             // 0..1535
            int row = idx >> 2, c4 = idx & 3;
            float4 wv = *(const float4*)(w + (size_t)row * 128 + chunk * 16 + c4 * 4);
            *(float2*)&w_sh[row][c4 * 4]     = make_float2(wv.x, wv.y);
            *(float2*)&w_sh[row][c4 * 4 + 2] = make_float2(wv.z, wv.w);
        }
        __syncthreads();
        // compute: unit = (row, quad of 4 tokens); 3 units per thread
        #pragma unroll
        for (int k = 0; k < 3; ++k) {
            int u = t + k * 512;
            int row = u >> 2, quad = u & 3;
            #pragma unroll
            for (int c16 = 0; c16 < 4; ++c16) {
                float2 wa = *(const float2*)&w_sh[row][c16 * 4];
                float2 wb = *(const float2*)&w_sh[row][c16 * 4 + 2];
                #pragma unroll
                for (int j = 0; j < 4; ++j) {
                    float4 xv = *(const float4*)&xst[quad * 4 + j][chunk * 16 + c16 * 4];
                    acc[k][j] += wa.x * xv.x + wa.y * xv.y + wb.x * xv.z + wb.y * xv.w;
                }
            }
        }
    }

    // pack into LDS (verified hi/lo layout), then vectorized stores
    #pragma unroll
    for (int k = 0; k < 3; ++k) {
        int u = t + k * 512;
        int row = u >> 2, quad = u & 3;
        int hh = row / 96, r = row - hh * 96;
        if (r < 64) {
            int rr = r & 31, part = rr >> 4, d = rr & 15;
            float sc = (r < 32) ? SCALE : 1.0f;
            #pragma unroll
            for (int j = 0; j < 4; ++j) {
                int tok = quad * 4 + j;
                float f = acc[k][j] * sc;
                unsigned u32 = __float_as_uint(f);
                float lo = f - __uint_as_float(u32 & 0xFFFF0000u);
                unsigned short hi16 = (unsigned short)(u32 >> 16);
                unsigned short lo16 = (unsigned short)(__float_as_uint(lo) >> 16);
                if (r < 32) {
                    qsh[hh][tok][part * 32 + d]      = hi16;
                    qsh[hh][tok][part * 32 + d + 16] = lo16;
                } else {
                    ksh[hh][tok][part * 32 + d]      = hi16;
                    ksh[hh][tok][part * 32 + d + 16] = lo16;
                }
            }
        } else {
            int d = r - 64;
            #pragma unroll
            for (int j = 0; j < 4; ++j)
                vsh[hh][d][quad * 4 + j] = bf_rne(acc[k][j]);
        }
    }
    __syncthreads();
    {   // qA/kB: 64 records x 8 granules of 16B = 512 stores each
        int rec = t >> 3, ch8 = t & 7;
        int hh  = rec >> 4, i = rec & 15;
        size_t base = ((size_t)hh * N_TOK + n0 + i) * 64 + ch8 * 8;
        *(uint4*)(qA + base) = *(const uint4*)&qsh[hh][i][ch8 * 8];
        *(uint4*)(kB + base) = *(const uint4*)&ksh[hh][i][ch8 * 8];
    }
    if (t < 256) {  // vT: 128 rows x 2 stores of 16B (8 tokens)
        int hh = t >> 6, d = (t >> 1) & 31, half = t & 1;
        *(uint4*)(vT + ((size_t)hh * 32 + d) * N_TOK + n0 + half * 8) =
            *(const uint4*)&vsh[hh][d][half * 8];
    }
}

// ---------------------------------------------------------------------------
// Kernel 2: MFMA flash diff-attention v5 = R6's verified staged structure,
// 16 queries/block -> 1024 blocks, 28 KB LDS -> 4-5 blocks/CU so barrier
// drains overlap across independent blocks.
// 64-key tiles staged async (global_load_lds dwordx4, double-buffered, XOR
// granule swizzle on the GLOBAL source side); wave w takes tile keys
// [w*16,(w+1)*16). In-register S^T->PV trick (R5-verified): S^T = K.Q^T via
// 16x16x32 (A=K hi|lo, B=Q); C-layout == A-layout of 16x16x16bf16_1k PV.
// Merge 4 wave-partials via LDS atomics; fused finalize.
// ---------------------------------------------------------------------------
__global__ __launch_bounds__(256, 4) void flash_kernel(
    const unsigned short* __restrict__ qA, const unsigned short* __restrict__ kB,
    const unsigned short* __restrict__ vT, float* __restrict__ out)
{
    __shared__ __align__(16) unsigned short kv_sh[2][6144]; // 24 KB: K 8K + V 4K per buf
    __shared__ float Obuf[2][16][32];                       // 4 KB
    __shared__ float lbuf[2][16];

    const int t    = threadIdx.x;
    const int w    = t >> 6;
    const int lane = t & 63;
    const int m    = lane & 15;
    const int quad = lane >> 4;
    const int h     = blockIdx.x >> 8;
    const int qbase = (blockIdx.x & 255) * 16;

    const unsigned short* kBh = kB + (size_t)h * N_TOK * 64;
    const unsigned short* vTh = vT + (size_t)h * 32 * N_TOK;

    // ---- async stage of one 64-key tile into buf b (768 granules) ----
    auto stage = [&](int tile, int b) {
        const unsigned short* kben = kBh + (size_t)tile * 64 * 64;
        #pragma unroll
        for (int i = 0; i < 3; ++i) {
            int s = i * 256 + t;              // granule slot 0..767
            const unsigned short* src;
            if (s < 512) {                    // K: record ml, granule c
                int ml = s >> 3, p = s & 7, c = p ^ (ml & 7);
                src = kben + ml * 64 + c * 8;
            } else {                          // V: row d, granule c (8 keys)
                int s2 = s - 512;
                int d = s2 >> 3, p = s2 & 7, c = p ^ (d & 7);
                src = vTh + (size_t)d * N_TOK + tile * 64 + c * 8;
            }
            async_copy16(src, &kv_sh[b][s * 8]);
        }
    };

    stage(0, 0);

    for (int i = t; i < 1024; i += 256) ((float*)Obuf)[i] = 0.f;
    if (t < 32) ((float*)lbuf)[t] = 0.f;

    // B-operand query fragments (R5-verified construction)
    const unsigned short* qrec = qA + (size_t)(h * N_TOK + qbase + m) * 64;
    const bf16x8 zz = {0,0,0,0,0,0,0,0};
    bf16x8 Bq1h = *(const bf16x8*)(qrec + (quad & 1) * 8);
    bf16x8 Bq2h = *(const bf16x8*)(qrec + 32 + (quad & 1) * 8);
    bf16x8 Bq1l = (quad < 2) ? *(const bf16x8*)(qrec + 16 + quad * 8) : zz;
    bf16x8 Bq2l = (quad < 2) ? *(const bf16x8*)(qrec + 48 + quad * 8) : zz;

    f32x4 O1a = {0,0,0,0}, O1b = {0,0,0,0}, O2a = {0,0,0,0}, O2b = {0,0,0,0};
    float l1 = 0.f, l2 = 0.f;

    // fragment LDS addresses (swizzled granules) — R6-verified
    const int ml  = w * 16 + m;               // local key record
    const int sw  = ml & 7;
    const int ak1_off = ml * 64 + ((quad)     ^ sw) * 8;
    const int ak2_off = ml * 64 + ((4 + quad) ^ sw) * 8;
    const int vg  = 2 * w + (quad >> 1);      // V granule (pre-swizzle)
    const int vh  = (quad & 1) * 4;
    const int v0_off = 4096 + m        * 64 + (vg ^ (m & 7))        * 8 + vh;
    const int v1_off = 4096 + (16 + m) * 64 + (vg ^ ((16 + m) & 7)) * 8 + vh;

    for (int tile = 0; tile < 64; ++tile) {
        const int b = tile & 1;
        __syncthreads();                      // drains stage of buf b
        if (tile + 1 < 64) stage(tile + 1, b ^ 1);

        const unsigned short* buf = kv_sh[b];
        bf16x8 Ak1 = *(const bf16x8*)(buf + ak1_off);
        bf16x8 Ak2 = *(const bf16x8*)(buf + ak2_off);

        f32x4 s1 = {0,0,0,0}, s2 = {0,0,0,0};
        s1 = __builtin_amdgcn_mfma_f32_16x16x32_bf16(Ak1, Bq1h, s1, 0, 0, 0);
        s1 = __builtin_amdgcn_mfma_f32_16x16x32_bf16(Ak1, Bq1l, s1, 0, 0, 0);
        s2 = __builtin_amdgcn_mfma_f32_16x16x32_bf16(Ak2, Bq2h, s2, 0, 0, 0);
        s2 = __builtin_amdgcn_mfma_f32_16x16x32_bf16(Ak2, Bq2l, s2, 0, 0, 0);

        bf16x4 aP1, aP2;
        #pragma unroll
        for (int i = 0; i < 4; ++i) {
            float p1 = __expf(s1[i]);
            float p2 = __expf(s2[i]);
            l1 += p1; l2 += p2;
            aP1[i] = (short)(__float_as_uint(p1) >> 16);
            aP2[i] = (short)(__float_as_uint(p2) >> 16);
        }

        bf16x4 Vb0 = *(const bf16x4*)(buf + v0_off);
        bf16x4 Vb1 = *(const bf16x4*)(buf + v1_off);

        O1a = __builtin_amdgcn_mfma_f32_16x16x16bf16_1k(aP1, Vb0, O1a, 0, 0, 0);
        O1b = __builtin_amdgcn_mfma_f32_16x16x16bf16_1k(aP1, Vb1, O1b, 0, 0, 0);
        O2a = __builtin_amdgcn_mfma_f32_16x16x16bf16_1k(aP2, Vb0, O2a, 0, 0, 0);
        O2b = __builtin_amdgcn_mfma_f32_16x16x16bf16_1k(aP2, Vb1, O2b, 0, 0, 0);
    }

    // reduce l across quads (each lane covers keys {quad*4+i} of query m)
    l1 += __shfl_xor(l1, 16, 64); l1 += __shfl_xor(l1, 32, 64);
    l2 += __shfl_xor(l2, 16, 64); l2 += __shfl_xor(l2, 32, 64);
    if (lane < 16) {
        atomicAdd(&lbuf[0][m], l1);
        atomicAdd(&lbuf[1][m], l2);
    }
    #pragma unroll
    for (int i = 0; i < 4; ++i) {
        int r = quad * 4 + i;                 // query row
        atomicAdd(&Obuf[0][r][m],      O1a[i]);
        atomicAdd(&Obuf[0][r][16 + m], O1b[i]);
        atomicAdd(&Obuf[1][r][m],      O2a[i]);
        atomicAdd(&Obuf[1][r][16 + m], O2b[i]);
    }
    __syncthreads();

    for (int i = t; i < 512; i += 256) {
        int r = i >> 5, d = i & 31;
        float il1 = 1.0f    / lbuf[0][r];
        float il2 = LAMBDA_ / lbuf[1][r];
        out[(size_t)(h * N_TOK + qbase) * 32 + i] =
            Obuf[0][r][d] * il1 - Obuf[1][r][d] * il2;
    }
}

extern "C" void kernel_launch(void* const* d_in, const int* in_sizes, int n_in,
                              void* d_out, int out_size, void* d_ws, size_t ws_size,
                              hipStream_t stream) {
    const float* x = (const float*)d_in[0];   // (1,128,32,32,32)
    const float* w = (const float*)d_in[1];   // (384,128)
    float* out = (float*)d_out;               // [h][n][32] flat (verified R1)

    unsigned short* qA = (unsigned short*)d_ws;               // 2 MB
    unsigned short* kB = qA + (size_t)NH * N_TOK * 64;        // 2 MB
    unsigned short* vT = kB + (size_t)NH * N_TOK * 64;        // 1 MB

    qkv_kernel<<<256, 512, 0, stream>>>(x, w, qA, kB, vT);
    flash_kernel<<<1024, 256, 0, stream>>>(qA, kB, vT, out);
}

// Round 10
// 153.546 us; speedup vs baseline: 1.4096x; 1.0032x over previous
//
#include <hip/hip_runtime.h>

#define N_TOK 4096
#define NH    4

typedef __attribute__((ext_vector_type(8))) short bf16x8;
typedef __attribute__((ext_vector_type(4))) short bf16x4;
typedef __attribute__((ext_vector_type(4))) float f32x4;

static constexpr float SCALE   = 0.17677669529663687f;  // 32^-0.5
static constexpr float QSCALE  = 0.25503632254435463f;  // SCALE * log2(e)
static constexpr float LAMBDA_ = 0.1f;
#define PSTRIDE 1056   // floats per (qtile,ks) partial record

__device__ __forceinline__ unsigned short bf_rne(float f) {
    unsigned u = __float_as_uint(f);
    u += 0x7FFF + ((u >> 16) & 1);
    return (unsigned short)(u >> 16);
}

__device__ __forceinline__ void async_copy16(const unsigned short* g, unsigned short* l) {
    __builtin_amdgcn_global_load_lds(
        (const __attribute__((address_space(1))) void*)g,
        (__attribute__((address_space(3))) void*)l, 16, 0, 0);
}

// ---------------------------------------------------------------------------
// Kernel 1: qkv projection + operand packing (R8-verified structure).
// Only change vs R8: q scaled by QSCALE = SCALE*log2(e) so flash uses
// v_exp_f32 (exp2) directly.
//  qA[h][n][64] bf16: {q1hi q1lo q2hi q2lo}   kB likewise for k
//  vT[h][32][4096] bf16 (transposed, RNE)
// ---------------------------------------------------------------------------
__global__ __launch_bounds__(512) void qkv_kernel(
    const float* __restrict__ x, const float* __restrict__ w,
    unsigned short* __restrict__ qA, unsigned short* __restrict__ kB,
    unsigned short* __restrict__ vT)
{
    __shared__ __align__(16) float w_sh[384][18];
    __shared__ __align__(16) float xst[16][132];
    __shared__ __align__(16) unsigned short qsh[4][16][64];
    __shared__ __align__(16) unsigned short ksh[4][16][64];
    __shared__ __align__(16) unsigned short vsh[4][32][16];

    const int t  = threadIdx.x;
    const int n0 = blockIdx.x * 16;
    const int nh = n0 >> 8, nw = (n0 >> 4) & 15;
    const int xbase = nh * 2048 + nw * 64;

    #pragma unroll
    for (int k = 0; k < 4; ++k) {
        int idx = t + k * 512;
        int tok = idx & 15, ch = idx >> 4;
        xst[tok][ch] = x[(size_t)ch * 32768 + xbase + tok * 2];
    }

    float acc[3][4];
    #pragma unroll
    for (int k = 0; k < 3; ++k)
        #pragma unroll
        for (int j = 0; j < 4; ++j) acc[k][j] = 0.f;

    for (int chunk = 0; chunk < 8; ++chunk) {
        __syncthreads();
        #pragma unroll
        for (int k = 0; k < 3; ++k) {
            int idx = t + k * 512;
            int row = idx >> 2, c4 = idx & 3;
            float4 wv = *(const float4*)(w + (size_t)row * 128 + chunk * 16 + c4 * 4);
            *(float2*)&w_sh[row][c4 * 4]     = make_float2(wv.x, wv.y);
            *(float2*)&w_sh[row][c4 * 4 + 2] = make_float2(wv.z, wv.w);
        }
        __syncthreads();
        #pragma unroll
        for (int k = 0; k < 3; ++k) {
            int u = t + k * 512;
            int row = u >> 2, quad = u & 3;
            #pragma unroll
            for (int c16 = 0; c16 < 4; ++c16) {
                float2 wa = *(const float2*)&w_sh[row][c16 * 4];
                float2 wb = *(const float2*)&w_sh[row][c16 * 4 + 2];
                #pragma unroll
                for (int j = 0; j < 4; ++j) {
                    float4 xv = *(const float4*)&xst[quad * 4 + j][chunk * 16 + c16 * 4];
                    acc[k][j] += wa.x * xv.x + wa.y * xv.y + wb.x * xv.z + wb.y * xv.w;
                }
            }
        }
    }

    #pragma unroll
    for (int k = 0; k < 3; ++k) {
        int u = t + k * 512;
        int row = u >> 2, quad = u & 3;
        int hh = row / 96, r = row - hh * 96;
        if (r < 64) {
            int rr = r & 31, part = rr >> 4, d = rr & 15;
            float sc = (r < 32) ? QSCALE : 1.0f;
            #pragma unroll
            for (int j = 0; j < 4; ++j) {
                int tok = quad * 4 + j;
                float f = acc[k][j] * sc;
                unsigned u32 = __float_as_uint(f);
                float lo = f - __uint_as_float(u32 & 0xFFFF0000u);
                unsigned short hi16 = (unsigned short)(u32 >> 16);
                unsigned short lo16 = (unsigned short)(__float_as_uint(lo) >> 16);
                if (r < 32) {
                    qsh[hh][tok][part * 32 + d]      = hi16;
                    qsh[hh][tok][part * 32 + d + 16] = lo16;
                } else {
                    ksh[hh][tok][part * 32 + d]      = hi16;
                    ksh[hh][tok][part * 32 + d + 16] = lo16;
                }
            }
        } else {
            int d = r - 64;
            #pragma unroll
            for (int j = 0; j < 4; ++j)
                vsh[hh][d][quad * 4 + j] = bf_rne(acc[k][j]);
        }
    }
    __syncthreads();
    {
        int rec = t >> 3, ch8 = t & 7;
        int hh  = rec >> 4, i = rec & 15;
        size_t base = ((size_t)hh * N_TOK + n0 + i) * 64 + ch8 * 8;
        *(uint4*)(qA + base) = *(const uint4*)&qsh[hh][i][ch8 * 8];
        *(uint4*)(kB + base) = *(const uint4*)&ksh[hh][i][ch8 * 8];
    }
    if (t < 256) {
        int hh = t >> 6, d = (t >> 1) & 31, half = t & 1;
        *(uint4*)(vT + ((size_t)hh * 32 + d) * N_TOK + n0 + half * 8) =
            *(const uint4*)&vsh[hh][d][half * 8];
    }
}

// ---------------------------------------------------------------------------
// Kernel 2: MFMA flash diff-attention v6 — split-K for occupancy.
// 2048 blocks (4 h x 256 qtiles x 2 ksplits) x 128 thr (2 waves);
// each block: 16 queries x 2048 keys in 64 tiles of 32 keys, double-buffered
// async LDS staging (XOR granule swizzle, R6/R8-verified); wave w takes tile
// keys [w*16,(w+1)*16). LDS 16.5 KB -> 8 blocks/CU: barrier drains of one
// block overlap with 7 computing blocks.
// In-register S^T->PV trick (R5-verified). v_exp_f32 (log2e pre-folded into
// q) and v_perm_b32 packing cut per-tile VALU ~2x. Partials (O1,O2,l1,l2) ->
// ws; fixed-max softmax makes the split-K merge a pure add (kernel 3).
// ---------------------------------------------------------------------------
__global__ __launch_bounds__(128, 4) void flash_kernel(
    const unsigned short* __restrict__ qA, const unsigned short* __restrict__ kB,
    const unsigned short* __restrict__ vT, float* __restrict__ parts)
{
    __shared__ __align__(16) unsigned short kv_sh[2][3072]; // 2 x 6 KB (K 4K + V 2K)
    __shared__ float Obuf[2][16][32];                       // 4 KB
    __shared__ float lbuf[2][16];

    const int t    = threadIdx.x;
    const int w    = t >> 6;                  // 0..1
    const int lane = t & 63;
    const int m    = lane & 15;
    const int quad = lane >> 4;
    const int ks   = blockIdx.x & 1;
    const int qt   = (blockIdx.x >> 1) & 255;
    const int h    = blockIdx.x >> 9;
    const int qbase = qt * 16;

    const unsigned short* kBh = kB + (size_t)h * N_TOK * 64;
    const unsigned short* vTh = vT + (size_t)h * 32 * N_TOK;
    const int key0 = ks * 2048;

    // ---- async stage of one 32-key tile into buf b (384 granules) ----
    auto stage = [&](int tile, int b) {
        const int bk = key0 + tile * 32;
        const unsigned short* kben = kBh + (size_t)bk * 64;
        #pragma unroll
        for (int i = 0; i < 3; ++i) {
            int s = i * 128 + t;              // 0..383
            const unsigned short* src;
            if (s < 256) {                    // K: rec ml (0..31), granule c
                int ml = s >> 3, p = s & 7, c = p ^ (ml & 7);
                src = kben + ml * 64 + c * 8;
            } else {                          // V: row d, granule c (8 keys)
                int s2 = s - 256;
                int d = s2 >> 2, p = s2 & 3, c = p ^ (d & 3);
                src = vTh + (size_t)d * N_TOK + bk + c * 8;
            }
            async_copy16(src, &kv_sh[b][s * 8]);
        }
    };

    stage(0, 0);

    for (int i = t; i < 1024; i += 128) ((float*)Obuf)[i] = 0.f;
    if (t < 32) ((float*)lbuf)[t] = 0.f;

    // B-operand query fragments (R5-verified construction)
    const unsigned short* qrec = qA + (size_t)(h * N_TOK + qbase + m) * 64;
    const bf16x8 zz = {0,0,0,0,0,0,0,0};
    bf16x8 Bq1h = *(const bf16x8*)(qrec + (quad & 1) * 8);
    bf16x8 Bq2h = *(const bf16x8*)(qrec + 32 + (quad & 1) * 8);
    bf16x8 Bq1l = (quad < 2) ? *(const bf16x8*)(qrec + 16 + quad * 8) : zz;
    bf16x8 Bq2l = (quad < 2) ? *(const bf16x8*)(qrec + 48 + quad * 8) : zz;

    f32x4 O1a = {0,0,0,0}, O1b = {0,0,0,0}, O2a = {0,0,0,0}, O2b = {0,0,0,0};
    float l1 = 0.f, l2 = 0.f;

    // fragment LDS offsets (XOR-swizzled granules)
    const int ml  = w * 16 + m;
    const int sw  = ml & 7;
    const int ak1_off = ml * 64 + ((quad)     ^ sw) * 8;
    const int ak2_off = ml * 64 + ((4 + quad) ^ sw) * 8;
    const int vg  = 2 * w + (quad >> 1);
    const int vh  = (quad & 1) * 4;
    const int v0_off = 2048 + m        * 32 + (vg ^ (m & 3)) * 8 + vh;
    const int v1_off = 2048 + (16 + m) * 32 + (vg ^ (m & 3)) * 8 + vh;

    #pragma unroll 2
    for (int tile = 0; tile < 64; ++tile) {
        const int b = tile & 1;
        __syncthreads();                      // drains stage of buf b
        if (tile + 1 < 64) stage(tile + 1, b ^ 1);

        const unsigned short* buf = kv_sh[b];
        bf16x8 Ak1 = *(const bf16x8*)(buf + ak1_off);
        bf16x8 Ak2 = *(const bf16x8*)(buf + ak2_off);

        f32x4 s1 = {0,0,0,0}, s2 = {0,0,0,0};
        s1 = __builtin_amdgcn_mfma_f32_16x16x32_bf16(Ak1, Bq1h, s1, 0, 0, 0);
        s1 = __builtin_amdgcn_mfma_f32_16x16x32_bf16(Ak1, Bq1l, s1, 0, 0, 0);
        s2 = __builtin_amdgcn_mfma_f32_16x16x32_bf16(Ak2, Bq2h, s2, 0, 0, 0);
        s2 = __builtin_amdgcn_mfma_f32_16x16x32_bf16(Ak2, Bq2l, s2, 0, 0, 0);

        // v_exp_f32 (q pre-scaled by log2e) + perm-pack to bf16 (truncate)
        float p10 = __builtin_amdgcn_exp2f(s1[0]), p11 = __builtin_amdgcn_exp2f(s1[1]);
        float p12 = __builtin_amdgcn_exp2f(s1[2]), p13 = __builtin_amdgcn_exp2f(s1[3]);
        float p20 = __builtin_amdgcn_exp2f(s2[0]), p21 = __builtin_amdgcn_exp2f(s2[1]);
        float p22 = __builtin_amdgcn_exp2f(s2[2]), p23 = __builtin_amdgcn_exp2f(s2[3]);
        l1 += (p10 + p11) + (p12 + p13);
        l2 += (p20 + p21) + (p22 + p23);
        union { unsigned u[2]; bf16x4 v; } c1, c2;
        c1.u[0] = __builtin_amdgcn_perm(__float_as_uint(p11), __float_as_uint(p10), 0x07060302u);
        c1.u[1] = __builtin_amdgcn_perm(__float_as_uint(p13), __float_as_uint(p12), 0x07060302u);
        c2.u[0] = __builtin_amdgcn_perm(__float_as_uint(p21), __float_as_uint(p20), 0x07060302u);
        c2.u[1] = __builtin_amdgcn_perm(__float_as_uint(p23), __float_as_uint(p22), 0x07060302u);

        bf16x4 Vb0 = *(const bf16x4*)(buf + v0_off);
        bf16x4 Vb1 = *(const bf16x4*)(buf + v1_off);

        O1a = __builtin_amdgcn_mfma_f32_16x16x16bf16_1k(c1.v, Vb0, O1a, 0, 0, 0);
        O1b = __builtin_amdgcn_mfma_f32_16x16x16bf16_1k(c1.v, Vb1, O1b, 0, 0, 0);
        O2a = __builtin_amdgcn_mfma_f32_16x16x16bf16_1k(c2.v, Vb0, O2a, 0, 0, 0);
        O2b = __builtin_amdgcn_mfma_f32_16x16x16bf16_1k(c2.v, Vb1, O2b, 0, 0, 0);
    }

    // reduce l across quads; merge 2 wave-partials via LDS atomics
    l1 += __shfl_xor(l1, 16, 64); l1 += __shfl_xor(l1, 32, 64);
    l2 += __shfl_xor(l2, 16, 64); l2 += __shfl_xor(l2, 32, 64);
    if (lane < 16) {
        atomicAdd(&lbuf[0][m], l1);
        atomicAdd(&lbuf[1][m], l2);
    }
    #pragma unroll
    for (int i = 0; i < 4; ++i) {
        int r = quad * 4 + i;
        atomicAdd(&Obuf[0][r][m],      O1a[i]);
        atomicAdd(&Obuf[0][r][16 + m], O1b[i]);
        atomicAdd(&Obuf[1][r][m],      O2a[i]);
        atomicAdd(&Obuf[1][r][16 + m], O2b[i]);
    }
    __syncthreads();

    // store partial record: [O1 512][O2 512][l1 16][l2 16]
    float* dst = parts + (size_t)(((h * 256 + qt) * 2 + ks)) * PSTRIDE;
    for (int i = t; i < 1024; i += 128) dst[i] = ((const float*)Obuf)[i];
    if (t < 32) dst[1024 + t] = ((const float*)lbuf)[t];
}

// ---------------------------------------------------------------------------
// Kernel 3: split-K merge + finalize. out = (O1a+O1b)/(l1a+l1b) - λ(...)
// ---------------------------------------------------------------------------
__global__ __launch_bounds__(256) void merge_kernel(
    const float* __restrict__ parts, float* __restrict__ out)
{
    int idx = blockIdx.x * 256 + threadIdx.x;     // 524288
    int row = idx >> 5, d = idx & 31;
    int h = row >> 12, n = row & 4095;
    int qt = n >> 4, r = n & 15;
    const float* p0 = parts + (size_t)((h * 256 + qt) * 2) * PSTRIDE;
    const float* p1 = p0 + PSTRIDE;
    float o1 = p0[r * 32 + d]       + p1[r * 32 + d];
    float o2 = p0[512 + r * 32 + d] + p1[512 + r * 32 + d];
    float l1 = p0[1024 + r]         + p1[1024 + r];
    float l2 = p0[1040 + r]         + p1[1040 + r];
    out[idx] = o1 / l1 - LAMBDA_ * o2 / l2;
}

extern "C" void kernel_launch(void* const* d_in, const int* in_sizes, int n_in,
                              void* d_out, int out_size, void* d_ws, size_t ws_size,
                              hipStream_t stream) {
    const float* x = (const float*)d_in[0];   // (1,128,32,32,32)
    const float* w = (const float*)d_in[1];   // (384,128)
    float* out = (float*)d_out;               // [h][n][32] flat (verified R1)

    unsigned short* qA = (unsigned short*)d_ws;               // 2 MB
    unsigned short* kB = qA + (size_t)NH * N_TOK * 64;        // 2 MB
    unsigned short* vT = kB + (size_t)NH * N_TOK * 64;        // 1 MB
    float* parts = (float*)(vT + (size_t)NH * 32 * N_TOK);    // 2048*1056*4B = 8.65 MB

    qkv_kernel<<<256, 512, 0, stream>>>(x, w, qA, kB, vT);
    flash_kernel<<<2048, 128, 0, stream>>>(qA, kB, vT, parts);
    merge_kernel<<<2048, 256, 0, stream>>>(parts, out);
}

// Round 11
// 144.122 us; speedup vs baseline: 1.5017x; 1.0654x over previous
//
#include <hip/hip_runtime.h>

#define N_TOK 4096
#define NH    4

typedef __attribute__((ext_vector_type(8))) short bf16x8;
typedef __attribute__((ext_vector_type(4))) short bf16x4;
typedef __attribute__((ext_vector_type(4))) float f32x4;

static constexpr float SCALE   = 0.17677669529663687f;  // 32^-0.5
static constexpr float QSCALE  = 0.25503632254435463f;  // SCALE * log2(e)
static constexpr float LAMBDA_ = 0.1f;
#define PSTRIDE 2112   // floats per (h,qt,ks) partial record (32q block)

__device__ __forceinline__ unsigned short bf_rne(float f) {
    unsigned u = __float_as_uint(f);
    u += 0x7FFF + ((u >> 16) & 1);
    return (unsigned short)(u >> 16);
}

__device__ __forceinline__ void async_copy16(const unsigned short* g, unsigned short* l) {
    __builtin_amdgcn_global_load_lds(
        (const __attribute__((address_space(1))) void*)g,
        (__attribute__((address_space(3))) void*)l, 16, 0, 0);
}

// ---------------------------------------------------------------------------
// Kernel 1: qkv projection + operand packing (R8/R10-verified structure).
//  qA[h][n][64] bf16: {q1hi q1lo q2hi q2lo} (QSCALE folded)   kB likewise
//  vT2[h][kb=key/8][dim 0..31][8 keys] bf16 RNE  <-- granule-tiled (NEW):
//  makes flash's V LDS reads 2-way-bank (free) instead of 8-way.
// ---------------------------------------------------------------------------
__global__ __launch_bounds__(512) void qkv_kernel(
    const float* __restrict__ x, const float* __restrict__ w,
    unsigned short* __restrict__ qA, unsigned short* __restrict__ kB,
    unsigned short* __restrict__ vT)
{
    __shared__ __align__(16) float w_sh[384][18];
    __shared__ __align__(16) float xst[16][132];
    __shared__ __align__(16) unsigned short qsh[4][16][64];
    __shared__ __align__(16) unsigned short ksh[4][16][64];
    __shared__ __align__(16) unsigned short vsh[4][32][16];

    const int t  = threadIdx.x;
    const int n0 = blockIdx.x * 16;
    const int nh = n0 >> 8, nw = (n0 >> 4) & 15;
    const int xbase = nh * 2048 + nw * 64;

    #pragma unroll
    for (int k = 0; k < 4; ++k) {
        int idx = t + k * 512;
        int tok = idx & 15, ch = idx >> 4;
        xst[tok][ch] = x[(size_t)ch * 32768 + xbase + tok * 2];
    }

    float acc[3][4];
    #pragma unroll
    for (int k = 0; k < 3; ++k)
        #pragma unroll
        for (int j = 0; j < 4; ++j) acc[k][j] = 0.f;

    for (int chunk = 0; chunk < 8; ++chunk) {
        __syncthreads();
        #pragma unroll
        for (int k = 0; k < 3; ++k) {
            int idx = t + k * 512;
            int row = idx >> 2, c4 = idx & 3;
            float4 wv = *(const float4*)(w + (size_t)row * 128 + chunk * 16 + c4 * 4);
            *(float2*)&w_sh[row][c4 * 4]     = make_float2(wv.x, wv.y);
            *(float2*)&w_sh[row][c4 * 4 + 2] = make_float2(wv.z, wv.w);
        }
        __syncthreads();
        #pragma unroll
        for (int k = 0; k < 3; ++k) {
            int u = t + k * 512;
            int row = u >> 2, quad = u & 3;
            #pragma unroll
            for (int c16 = 0; c16 < 4; ++c16) {
                float2 wa = *(const float2*)&w_sh[row][c16 * 4];
                float2 wb = *(const float2*)&w_sh[row][c16 * 4 + 2];
                #pragma unroll
                for (int j = 0; j < 4; ++j) {
                    float4 xv = *(const float4*)&xst[quad * 4 + j][chunk * 16 + c16 * 4];
                    acc[k][j] += wa.x * xv.x + wa.y * xv.y + wb.x * xv.z + wb.y * xv.w;
                }
            }
        }
    }

    #pragma unroll
    for (int k = 0; k < 3; ++k) {
        int u = t + k * 512;
        int row = u >> 2, quad = u & 3;
        int hh = row / 96, r = row - hh * 96;
        if (r < 64) {
            int rr = r & 31, part = rr >> 4, d = rr & 15;
            float sc = (r < 32) ? QSCALE : 1.0f;
            #pragma unroll
            for (int j = 0; j < 4; ++j) {
                int tok = quad * 4 + j;
                float f = acc[k][j] * sc;
                unsigned u32 = __float_as_uint(f);
                float lo = f - __uint_as_float(u32 & 0xFFFF0000u);
                unsigned short hi16 = (unsigned short)(u32 >> 16);
                unsigned short lo16 = (unsigned short)(__float_as_uint(lo) >> 16);
                if (r < 32) {
                    qsh[hh][tok][part * 32 + d]      = hi16;
                    qsh[hh][tok][part * 32 + d + 16] = lo16;
                } else {
                    ksh[hh][tok][part * 32 + d]      = hi16;
                    ksh[hh][tok][part * 32 + d + 16] = lo16;
                }
            }
        } else {
            int d = r - 64;
            #pragma unroll
            for (int j = 0; j < 4; ++j)
                vsh[hh][d][quad * 4 + j] = bf_rne(acc[k][j]);
        }
    }
    __syncthreads();
    {
        int rec = t >> 3, ch8 = t & 7;
        int hh  = rec >> 4, i = rec & 15;
        size_t base = ((size_t)hh * N_TOK + n0 + i) * 64 + ch8 * 8;
        *(uint4*)(qA + base) = *(const uint4*)&qsh[hh][i][ch8 * 8];
        *(uint4*)(kB + base) = *(const uint4*)&ksh[hh][i][ch8 * 8];
    }
    if (t < 256) {  // vT2 granule-tiled: [h][kb][dim][8]
        int hh = t >> 6, d = (t >> 1) & 31, half = t & 1;
        int kb = (n0 >> 3) + half;
        *(uint4*)(vT + (size_t)hh * 131072 + kb * 256 + d * 8) =
            *(const uint4*)&vsh[hh][d][half * 8];
    }
}

// ---------------------------------------------------------------------------
// Kernel 2: MFMA flash diff-attention v7.
// 1024 blocks (4h x 128 qt32 x 2 ks) x 256 thr (4 waves). Block: 32 queries x
// 2048 keys -> K/V L2 re-read halved (~393 MB, ~11 us floor). 64-key tiles
// double-buffered via global_load_lds; ALL 4 waves share each tile: wave w ->
// qtile w>>1, key-half w&1, two independent 16-key slices per tile (ILP
// across the S->exp->PV chain). V granule-tiled layout -> 2-way banks (free).
// In-register S^T->PV trick (R5-verified). LDS 33 KB -> 4 blocks/CU.
// Wave partials merged via LDS atomics (once); parts -> merge kernel.
// ---------------------------------------------------------------------------
__global__ __launch_bounds__(256, 4) void flash_kernel(
    const unsigned short* __restrict__ qA, const unsigned short* __restrict__ kB,
    const unsigned short* __restrict__ vT, float* __restrict__ parts)
{
    __shared__ __align__(16) unsigned short kv_sh[2][6144]; // 2 x 12 KB (K 8K + V 4K)
    __shared__ float Obuf[2][2][16][32];                    // [qt][br][r][d] 8 KB
    __shared__ float lbuf[2][2][16];

    const int t    = threadIdx.x;
    const int w    = t >> 6;
    const int lane = t & 63;
    const int m    = lane & 15;
    const int quad = lane >> 4;
    const int ks   = blockIdx.x & 1;
    const int qt   = (blockIdx.x >> 1) & 127;
    const int h    = blockIdx.x >> 8;
    const int qtile = w >> 1;                 // 0..1
    const int kh    = w & 1;                  // key half within tile
    const int qbase = qt * 32;

    const unsigned short* kBh = kB + (size_t)h * N_TOK * 64;
    const unsigned short* vTh = vT + (size_t)h * 131072;
    const int key0 = ks * 2048;

    // ---- async stage of one 64-key tile into buf b (768 granules) ----
    auto stage = [&](int tile, int b) {
        const unsigned short* kben = kBh + (size_t)(key0 + tile * 64) * 64;
        const unsigned short* vben = vTh + (size_t)((key0 >> 3) + tile * 8) * 256;
        #pragma unroll
        for (int i = 0; i < 3; ++i) {
            int s = i * 256 + t;              // 0..767
            const unsigned short* src;
            if (s < 512) {                    // K: rec ml (0..63), XOR granule
                int ml = s >> 3, p = s & 7, c = p ^ (ml & 7);
                src = kben + ml * 64 + c * 8;
            } else {                          // V: granule (kb_l, dim)
                int s2 = s - 512;
                int kb_l = s2 >> 5, d = s2 & 31;
                src = vben + kb_l * 256 + d * 8;
            }
            async_copy16(src, &kv_sh[b][s * 8]);
        }
    };

    stage(0, 0);

    for (int i = t; i < 2048; i += 256) ((float*)Obuf)[i] = 0.f;
    if (t < 64) ((float*)lbuf)[t] = 0.f;

    // B-operand query fragments (R5-verified construction)
    const unsigned short* qrec = qA + (size_t)(h * N_TOK + qbase + qtile * 16 + m) * 64;
    const bf16x8 zz = {0,0,0,0,0,0,0,0};
    bf16x8 Bq1h = *(const bf16x8*)(qrec + (quad & 1) * 8);
    bf16x8 Bq2h = *(const bf16x8*)(qrec + 32 + (quad & 1) * 8);
    bf16x8 Bq1l = (quad < 2) ? *(const bf16x8*)(qrec + 16 + quad * 8) : zz;
    bf16x8 Bq2l = (quad < 2) ? *(const bf16x8*)(qrec + 48 + quad * 8) : zz;

    f32x4 O1a = {0,0,0,0}, O1b = {0,0,0,0}, O2a = {0,0,0,0}, O2b = {0,0,0,0};
    float l1 = 0.f, l2 = 0.f;

    // K fragment LDS offsets (shorts), slices 0/1
    const int ml0 = kh * 32 + m, ml1 = ml0 + 16;
    const int a1o0 = ml0 * 64 + ((quad)     ^ (ml0 & 7)) * 8;
    const int a2o0 = ml0 * 64 + ((4 + quad) ^ (ml0 & 7)) * 8;
    const int a1o1 = ml1 * 64 + ((quad)     ^ (ml1 & 7)) * 8;
    const int a2o1 = ml1 * 64 + ((4 + quad) ^ (ml1 & 7)) * 8;
    // V offsets: granule (kb_l, dim), 8B sub-offset by quad parity
    const int kbl0 = kh * 4 + (quad >> 1);
    const int v0o0 = 4096 + (kbl0 * 32 + m)      * 8 + (quad & 1) * 4;
    const int v1o0 = 4096 + (kbl0 * 32 + 16 + m) * 8 + (quad & 1) * 4;
    const int v0o1 = v0o0 + 512;              // slice1: +2 granule-groups
    const int v1o1 = v1o0 + 512;

    for (int tile = 0; tile < 32; ++tile) {
        const int b = tile & 1;
        __syncthreads();                      // drains stage of buf b
        if (tile + 1 < 32) stage(tile + 1, b ^ 1);

        const unsigned short* buf = kv_sh[b];
        bf16x8 K1_0 = *(const bf16x8*)(buf + a1o0);
        bf16x8 K2_0 = *(const bf16x8*)(buf + a2o0);
        bf16x8 K1_1 = *(const bf16x8*)(buf + a1o1);
        bf16x8 K2_1 = *(const bf16x8*)(buf + a2o1);

        f32x4 sA1 = {0,0,0,0}, sA2 = {0,0,0,0};
        f32x4 sB1 = {0,0,0,0}, sB2 = {0,0,0,0};
        sA1 = __builtin_amdgcn_mfma_f32_16x16x32_bf16(K1_0, Bq1h, sA1, 0, 0, 0);
        sB1 = __builtin_amdgcn_mfma_f32_16x16x32_bf16(K1_1, Bq1h, sB1, 0, 0, 0);
        sA1 = __builtin_amdgcn_mfma_f32_16x16x32_bf16(K1_0, Bq1l, sA1, 0, 0, 0);
        sB1 = __builtin_amdgcn_mfma_f32_16x16x32_bf16(K1_1, Bq1l, sB1, 0, 0, 0);
        sA2 = __builtin_amdgcn_mfma_f32_16x16x32_bf16(K2_0, Bq2h, sA2, 0, 0, 0);
        sB2 = __builtin_amdgcn_mfma_f32_16x16x32_bf16(K2_1, Bq2h, sB2, 0, 0, 0);
        sA2 = __builtin_amdgcn_mfma_f32_16x16x32_bf16(K2_0, Bq2l, sA2, 0, 0, 0);
        sB2 = __builtin_amdgcn_mfma_f32_16x16x32_bf16(K2_1, Bq2l, sB2, 0, 0, 0);

        // exp2 + perm-pack, both slices (independent chains)
        float pa0 = __builtin_amdgcn_exp2f(sA1[0]), pa1 = __builtin_amdgcn_exp2f(sA1[1]);
        float pa2 = __builtin_amdgcn_exp2f(sA1[2]), pa3 = __builtin_amdgcn_exp2f(sA1[3]);
        float pb0 = __builtin_amdgcn_exp2f(sB1[0]), pb1 = __builtin_amdgcn_exp2f(sB1[1]);
        float pb2 = __builtin_amdgcn_exp2f(sB1[2]), pb3 = __builtin_amdgcn_exp2f(sB1[3]);
        float qa0 = __builtin_amdgcn_exp2f(sA2[0]), qa1 = __builtin_amdgcn_exp2f(sA2[1]);
        float qa2 = __builtin_amdgcn_exp2f(sA2[2]), qa3 = __builtin_amdgcn_exp2f(sA2[3]);
        float qb0 = __builtin_amdgcn_exp2f(sB2[0]), qb1 = __builtin_amdgcn_exp2f(sB2[1]);
        float qb2 = __builtin_amdgcn_exp2f(sB2[2]), qb3 = __builtin_amdgcn_exp2f(sB2[3]);
        l1 += (pa0 + pa1) + (pa2 + pa3) + (pb0 + pb1) + (pb2 + pb3);
        l2 += (qa0 + qa1) + (qa2 + qa3) + (qb0 + qb1) + (qb2 + qb3);
        union { unsigned u[2]; bf16x4 v; } cA1, cB1, cA2, cB2;
        cA1.u[0] = __builtin_amdgcn_perm(__float_as_uint(pa1), __float_as_uint(pa0), 0x07060302u);
        cA1.u[1] = __builtin_amdgcn_perm(__float_as_uint(pa3), __float_as_uint(pa2), 0x07060302u);
        cB1.u[0] = __builtin_amdgcn_perm(__float_as_uint(pb1), __float_as_uint(pb0), 0x07060302u);
        cB1.u[1] = __builtin_amdgcn_perm(__float_as_uint(pb3), __float_as_uint(pb2), 0x07060302u);
        cA2.u[0] = __builtin_amdgcn_perm(__float_as_uint(qa1), __float_as_uint(qa0), 0x07060302u);
        cA2.u[1] = __builtin_amdgcn_perm(__float_as_uint(qa3), __float_as_uint(qa2), 0x07060302u);
        cB2.u[0] = __builtin_amdgcn_perm(__float_as_uint(qb1), __float_as_uint(qb0), 0x07060302u);
        cB2.u[1] = __builtin_amdgcn_perm(__float_as_uint(qb3), __float_as_uint(qb2), 0x07060302u);

        bf16x4 V00 = *(const bf16x4*)(buf + v0o0);
        bf16x4 V10 = *(const bf16x4*)(buf + v1o0);
        bf16x4 V01 = *(const bf16x4*)(buf + v0o1);
        bf16x4 V11 = *(const bf16x4*)(buf + v1o1);

        O1a = __builtin_amdgcn_mfma_f32_16x16x16bf16_1k(cA1.v, V00, O1a, 0, 0, 0);
        O1b = __builtin_amdgcn_mfma_f32_16x16x16bf16_1k(cA1.v, V10, O1b, 0, 0, 0);
        O2a = __builtin_amdgcn_mfma_f32_16x16x16bf16_1k(cA2.v, V00, O2a, 0, 0, 0);
        O2b = __builtin_amdgcn_mfma_f32_16x16x16bf16_1k(cA2.v, V10, O2b, 0, 0, 0);
        O1a = __builtin_amdgcn_mfma_f32_16x16x16bf16_1k(cB1.v, V01, O1a, 0, 0, 0);
        O1b = __builtin_amdgcn_mfma_f32_16x16x16bf16_1k(cB1.v, V11, O1b, 0, 0, 0);
        O2a = __builtin_amdgcn_mfma_f32_16x16x16bf16_1k(cB2.v, V01, O2a, 0, 0, 0);
        O2b = __builtin_amdgcn_mfma_f32_16x16x16bf16_1k(cB2.v, V11, O2b, 0, 0, 0);
    }

    // reduce l across quads, merge wave partials via LDS atomics (once)
    l1 += __shfl_xor(l1, 16, 64); l1 += __shfl_xor(l1, 32, 64);
    l2 += __shfl_xor(l2, 16, 64); l2 += __shfl_xor(l2, 32, 64);
    if (lane < 16) {
        atomicAdd(&lbuf[qtile][0][m], l1);
        atomicAdd(&lbuf[qtile][1][m], l2);
    }
    #pragma unroll
    for (int i = 0; i < 4; ++i) {
        int r = quad * 4 + i;
        atomicAdd(&Obuf[qtile][0][r][m],      O1a[i]);
        atomicAdd(&Obuf[qtile][0][r][16 + m], O1b[i]);
        atomicAdd(&Obuf[qtile][1][r][m],      O2a[i]);
        atomicAdd(&Obuf[qtile][1][r][16 + m], O2b[i]);
    }
    __syncthreads();

    // store partial record: [O1 1024][O2 1024][l1 32][l2 32]
    float* dst = parts + (size_t)((h * 128 + qt) * 2 + ks) * PSTRIDE;
    for (int i = t; i < 1024; i += 256) {
        int r = i >> 5, d = i & 31;
        int qtl = r >> 4, rl = r & 15;
        dst[i]        = Obuf[qtl][0][rl][d];
        dst[1024 + i] = Obuf[qtl][1][rl][d];
    }
    if (t < 32) {
        int qtl = t >> 4, rl = t & 15;
        dst[2048 + t] = lbuf[qtl][0][rl];
        dst[2080 + t] = lbuf[qtl][1][rl];
    }
}

// ---------------------------------------------------------------------------
// Kernel 3: split-K merge + finalize. out = ΣO1/Σl1 - λ ΣO2/Σl2
// ---------------------------------------------------------------------------
__global__ __launch_bounds__(256) void merge_kernel(
    const float* __restrict__ parts, float* __restrict__ out)
{
    int idx = blockIdx.x * 256 + threadIdx.x;     // 524288
    int row = idx >> 5, d = idx & 31;
    int h = row >> 12, n = row & 4095;
    int qt = n >> 5, r = n & 31;
    const float* p0 = parts + (size_t)((h * 128 + qt) * 2) * PSTRIDE;
    const float* p1 = p0 + PSTRIDE;
    float o1 = p0[r * 32 + d]        + p1[r * 32 + d];
    float o2 = p0[1024 + r * 32 + d] + p1[1024 + r * 32 + d];
    float l1 = p0[2048 + r]          + p1[2048 + r];
    float l2 = p0[2080 + r]          + p1[2080 + r];
    out[idx] = o1 / l1 - LAMBDA_ * o2 / l2;
}

extern "C" void kernel_launch(void* const* d_in, const int* in_sizes, int n_in,
                              void* d_out, int out_size, void* d_ws, size_t ws_size,
                              hipStream_t stream) {
    const float* x = (const float*)d_in[0];   // (1,128,32,32,32)
    const float* w = (const float*)d_in[1];   // (384,128)
    float* out = (float*)d_out;               // [h][n][32] flat (verified R1)

    unsigned short* qA = (unsigned short*)d_ws;               // 2 MB
    unsigned short* kB = qA + (size_t)NH * N_TOK * 64;        // 2 MB
    unsigned short* vT = kB + (size_t)NH * N_TOK * 64;        // 1 MB
    float* parts = (float*)(vT + (size_t)NH * 32 * N_TOK);    // 1024*2112*4B = 8.65 MB

    qkv_kernel<<<256, 512, 0, stream>>>(x, w, qA, kB, vT);
    flash_kernel<<<1024, 256, 0, stream>>>(qA, kB, vT, parts);
    merge_kernel<<<2048, 256, 0, stream>>>(parts, out);
}

// Round 12
// 134.174 us; speedup vs baseline: 1.6131x; 1.0741x over previous
//
#include <hip/hip_runtime.h>

#define N_TOK 4096
#define NH    4

typedef __attribute__((ext_vector_type(8))) short bf16x8;
typedef __attribute__((ext_vector_type(4))) short bf16x4;
typedef __attribute__((ext_vector_type(4))) float f32x4;

static constexpr float SCALE   = 0.17677669529663687f;  // 32^-0.5
static constexpr float QSCALE  = 0.25503632254435463f;  // SCALE * log2(e)
static constexpr float LAMBDA_ = 0.1f;
#define PSTRIDE 2112   // floats per (h,qt,ks) partial record (32q block)

__device__ __forceinline__ unsigned short bf_rne(float f) {
    unsigned u = __float_as_uint(f);
    u += 0x7FFF + ((u >> 16) & 1);
    return (unsigned short)(u >> 16);
}

__device__ __forceinline__ void async_copy16(const unsigned short* g, unsigned short* l) {
    __builtin_amdgcn_global_load_lds(
        (const __attribute__((address_space(1))) void*)g,
        (__attribute__((address_space(3))) void*)l, 16, 0, 0);
}

// ---------------------------------------------------------------------------
// Kernel 0: w -> bf16 hi/lo split (QSCALE folded into q rows). 384x128.
// ---------------------------------------------------------------------------
__global__ __launch_bounds__(256) void prep_w_kernel(
    const float* __restrict__ w,
    unsigned short* __restrict__ wh, unsigned short* __restrict__ wl)
{
    int idx = blockIdx.x * 256 + threadIdx.x;     // 49152
    int row = idx >> 7;
    int rr  = row % 96;
    float sc = (rr < 32) ? QSCALE : 1.0f;
    float f  = w[idx] * sc;
    unsigned u = __float_as_uint(f);
    float lo = f - __uint_as_float(u & 0xFFFF0000u);
    wh[idx] = (unsigned short)(u >> 16);
    wl[idx] = (unsigned short)(__float_as_uint(lo) >> 16);
}

// ---------------------------------------------------------------------------
// Kernel 1: qkv projection via MFMA (replaces the LDS-broadcast VALU GEMM,
// which was LDS-BW bound at ~30-40us). Block = (tok-group of 16, row-half of
// 192); 256 thr = 4 waves, 3 row-tiles each. x staged to LDS once, split to
// bf16 hi/lo (stride 136 shorts -> 2-way banks, free). C = AhBh + AlBh + AhBl
// (w hi/lo from prep; x hi/lo from LDS) = 12 MFMA per row-tile -> fp32-like
// precision. C-layout (R5-verified): col=lane&15=token, row=quad*4+i=w-row.
// Epilogue packs into the SAME verified qA/kB/vT layouts as R11.
//  qA[h][n][64] bf16: {q1hi q1lo q2hi q2lo} (QSCALE folded)   kB likewise
//  vT[h][kb=key/8][dim][8keys] bf16 RNE (granule-tiled)
// ---------------------------------------------------------------------------
__global__ __launch_bounds__(256) void qkv_kernel(
    const float* __restrict__ x,
    const unsigned short* __restrict__ wh, const unsigned short* __restrict__ wl,
    unsigned short* __restrict__ qA, unsigned short* __restrict__ kB,
    unsigned short* __restrict__ vT)
{
    __shared__ __align__(16) float xf[16][132];
    __shared__ __align__(16) unsigned short xbh[16 * 136];
    __shared__ __align__(16) unsigned short xbl[16 * 136];
    __shared__ __align__(16) unsigned short qsh[2][16][64];
    __shared__ __align__(16) unsigned short ksh[2][16][64];
    __shared__ __align__(16) unsigned short vsh[2][32][16];

    const int t  = threadIdx.x;
    const int tg = blockIdx.x >> 1;
    const int rh = blockIdx.x & 1;            // row half: heads {2rh, 2rh+1}
    const int n0 = tg * 16;
    const int nh = n0 >> 8, nw = (n0 >> 4) & 15;
    const int xbase = nh * 2048 + nw * 64;

    #pragma unroll
    for (int k = 0; k < 8; ++k) {
        int idx = t + k * 256;
        int tok = idx & 15, ch = idx >> 4;
        xf[tok][ch] = x[(size_t)ch * 32768 + xbase + tok * 2];
    }
    __syncthreads();
    #pragma unroll
    for (int k = 0; k < 8; ++k) {
        int idx = t + k * 256;
        int tok = idx & 15, ch = idx >> 4;
        float f = xf[tok][ch];
        unsigned u = __float_as_uint(f);
        float lo = f - __uint_as_float(u & 0xFFFF0000u);
        xbh[tok * 136 + ch] = (unsigned short)(u >> 16);
        xbl[tok * 136 + ch] = (unsigned short)(__float_as_uint(lo) >> 16);
    }
    __syncthreads();

    const int lane = t & 63;
    const int m    = lane & 15;
    const int quad = lane >> 4;
    const int w    = t >> 6;

    // B-operand (tokens) fragments, shared across row-tiles
    bf16x8 Bh[4], Bl[4];
    #pragma unroll
    for (int s = 0; s < 4; ++s) {
        Bh[s] = *(const bf16x8*)&xbh[m * 136 + s * 32 + quad * 8];
        Bl[s] = *(const bf16x8*)&xbl[m * 136 + s * 32 + quad * 8];
    }

    #pragma unroll
    for (int rt = 0; rt < 3; ++rt) {
        const int R0 = rh * 192 + w * 48 + rt * 16;
        const unsigned short* whp = wh + (size_t)(R0 + m) * 128;
        const unsigned short* wlp = wl + (size_t)(R0 + m) * 128;
        bf16x8 Ah[4], Al[4];
        #pragma unroll
        for (int s = 0; s < 4; ++s) {
            Ah[s] = *(const bf16x8*)(whp + s * 32 + quad * 8);
            Al[s] = *(const bf16x8*)(wlp + s * 32 + quad * 8);
        }
        f32x4 C = {0, 0, 0, 0};
        #pragma unroll
        for (int s = 0; s < 4; ++s) {
            C = __builtin_amdgcn_mfma_f32_16x16x32_bf16(Ah[s], Bh[s], C, 0, 0, 0);
            C = __builtin_amdgcn_mfma_f32_16x16x32_bf16(Al[s], Bh[s], C, 0, 0, 0);
            C = __builtin_amdgcn_mfma_f32_16x16x32_bf16(Ah[s], Bl[s], C, 0, 0, 0);
        }
        // epilogue: lane holds token m, rows R0+quad*4+i (type is tile-uniform)
        #pragma unroll
        for (int i = 0; i < 4; ++i) {
            int R  = R0 + quad * 4 + i;
            int hh = R / 96;
            int rr = R - hh * 96;
            int hl = hh & 1;
            float f = C[i];
            if (rr < 64) {
                unsigned u = __float_as_uint(f);
                float lo = f - __uint_as_float(u & 0xFFFF0000u);
                unsigned short hi16 = (unsigned short)(u >> 16);
                unsigned short lo16 = (unsigned short)(__float_as_uint(lo) >> 16);
                int part = (rr & 31) >> 4, d = rr & 15;
                if (rr < 32) {
                    qsh[hl][m][part * 32 + d]      = hi16;
                    qsh[hl][m][part * 32 + d + 16] = lo16;
                } else {
                    ksh[hl][m][part * 32 + d]      = hi16;
                    ksh[hl][m][part * 32 + d + 16] = lo16;
                }
            } else {
                vsh[hl][rr - 64][m] = bf_rne(f);
            }
        }
    }
    __syncthreads();

    {   // qA/kB: 32 records (2 heads x 16 tok) x 8 granules of 16B
        int rec = t >> 3, ch8 = t & 7;
        int hl  = rec >> 4, i = rec & 15;
        int hh  = rh * 2 + hl;
        size_t base = ((size_t)hh * N_TOK + n0 + i) * 64 + ch8 * 8;
        *(uint4*)(qA + base) = *(const uint4*)&qsh[hl][i][ch8 * 8];
        *(uint4*)(kB + base) = *(const uint4*)&ksh[hl][i][ch8 * 8];
    }
    if (t < 128) {  // vT granule-tiled: [h][kb][dim][8]
        int hl = t >> 6, d = (t >> 1) & 31, half = t & 1;
        int hh = rh * 2 + hl;
        int kb = (n0 >> 3) + half;
        *(uint4*)(vT + (size_t)hh * 131072 + kb * 256 + d * 8) =
            *(const uint4*)&vsh[hl][d][half * 8];
    }
}

// ---------------------------------------------------------------------------
// Kernel 2: MFMA flash diff-attention v7 (VERBATIM from R11, passing @64us).
// ---------------------------------------------------------------------------
__global__ __launch_bounds__(256, 4) void flash_kernel(
    const unsigned short* __restrict__ qA, const unsigned short* __restrict__ kB,
    const unsigned short* __restrict__ vT, float* __restrict__ parts)
{
    __shared__ __align__(16) unsigned short kv_sh[2][6144]; // 2 x 12 KB (K 8K + V 4K)
    __shared__ float Obuf[2][2][16][32];                    // [qt][br][r][d] 8 KB
    __shared__ float lbuf[2][2][16];

    const int t    = threadIdx.x;
    const int w    = t >> 6;
    const int lane = t & 63;
    const int m    = lane & 15;
    const int quad = lane >> 4;
    const int ks   = blockIdx.x & 1;
    const int qt   = (blockIdx.x >> 1) & 127;
    const int h    = blockIdx.x >> 8;
    const int qtile = w >> 1;                 // 0..1
    const int kh    = w & 1;                  // key half within tile
    const int qbase = qt * 32;

    const unsigned short* kBh = kB + (size_t)h * N_TOK * 64;
    const unsigned short* vTh = vT + (size_t)h * 131072;
    const int key0 = ks * 2048;

    auto stage = [&](int tile, int b) {
        const unsigned short* kben = kBh + (size_t)(key0 + tile * 64) * 64;
        const unsigned short* vben = vTh + (size_t)((key0 >> 3) + tile * 8) * 256;
        #pragma unroll
        for (int i = 0; i < 3; ++i) {
            int s = i * 256 + t;              // 0..767
            const unsigned short* src;
            if (s < 512) {                    // K: rec ml (0..63), XOR granule
                int ml = s >> 3, p = s & 7, c = p ^ (ml & 7);
                src = kben + ml * 64 + c * 8;
            } else {                          // V: granule (kb_l, dim)
                int s2 = s - 512;
                int kb_l = s2 >> 5, d = s2 & 31;
                src = vben + kb_l * 256 + d * 8;
            }
            async_copy16(src, &kv_sh[b][s * 8]);
        }
    };

    stage(0, 0);

    for (int i = t; i < 2048; i += 256) ((float*)Obuf)[i] = 0.f;
    if (t < 64) ((float*)lbuf)[t] = 0.f;

    const unsigned short* qrec = qA + (size_t)(h * N_TOK + qbase + qtile * 16 + m) * 64;
    const bf16x8 zz = {0,0,0,0,0,0,0,0};
    bf16x8 Bq1h = *(const bf16x8*)(qrec + (quad & 1) * 8);
    bf16x8 Bq2h = *(const bf16x8*)(qrec + 32 + (quad & 1) * 8);
    bf16x8 Bq1l = (quad < 2) ? *(const bf16x8*)(qrec + 16 + quad * 8) : zz;
    bf16x8 Bq2l = (quad < 2) ? *(const bf16x8*)(qrec + 48 + quad * 8) : zz;

    f32x4 O1a = {0,0,0,0}, O1b = {0,0,0,0}, O2a = {0,0,0,0}, O2b = {0,0,0,0};
    float l1 = 0.f, l2 = 0.f;

    const int ml0 = kh * 32 + m, ml1 = ml0 + 16;
    const int a1o0 = ml0 * 64 + ((quad)     ^ (ml0 & 7)) * 8;
    const int a2o0 = ml0 * 64 + ((4 + quad) ^ (ml0 & 7)) * 8;
    const int a1o1 = ml1 * 64 + ((quad)     ^ (ml1 & 7)) * 8;
    const int a2o1 = ml1 * 64 + ((4 + quad) ^ (ml1 & 7)) * 8;
    const int kbl0 = kh * 4 + (quad >> 1);
    const int v0o0 = 4096 + (kbl0 * 32 + m)      * 8 + (quad & 1) * 4;
    const int v1o0 = 4096 + (kbl0 * 32 + 16 + m) * 8 + (quad & 1) * 4;
    const int v0o1 = v0o0 + 512;
    const int v1o1 = v1o0 + 512;

    for (int tile = 0; tile < 32; ++tile) {
        const int b = tile & 1;
        __syncthreads();
        if (tile + 1 < 32) stage(tile + 1, b ^ 1);

        const unsigned short* buf = kv_sh[b];
        bf16x8 K1_0 = *(const bf16x8*)(buf + a1o0);
        bf16x8 K2_0 = *(const bf16x8*)(buf + a2o0);
        bf16x8 K1_1 = *(const bf16x8*)(buf + a1o1);
        bf16x8 K2_1 = *(const bf16x8*)(buf + a2o1);

        f32x4 sA1 = {0,0,0,0}, sA2 = {0,0,0,0};
        f32x4 sB1 = {0,0,0,0}, sB2 = {0,0,0,0};
        sA1 = __builtin_amdgcn_mfma_f32_16x16x32_bf16(K1_0, Bq1h, sA1, 0, 0, 0);
        sB1 = __builtin_amdgcn_mfma_f32_16x16x32_bf16(K1_1, Bq1h, sB1, 0, 0, 0);
        sA1 = __builtin_amdgcn_mfma_f32_16x16x32_bf16(K1_0, Bq1l, sA1, 0, 0, 0);
        sB1 = __builtin_amdgcn_mfma_f32_16x16x32_bf16(K1_1, Bq1l, sB1, 0, 0, 0);
        sA2 = __builtin_amdgcn_mfma_f32_16x16x32_bf16(K2_0, Bq2h, sA2, 0, 0, 0);
        sB2 = __builtin_amdgcn_mfma_f32_16x16x32_bf16(K2_1, Bq2h, sB2, 0, 0, 0);
        sA2 = __builtin_amdgcn_mfma_f32_16x16x32_bf16(K2_0, Bq2l, sA2, 0, 0, 0);
        sB2 = __builtin_amdgcn_mfma_f32_16x16x32_bf16(K2_1, Bq2l, sB2, 0, 0, 0);

        float pa0 = __builtin_amdgcn_exp2f(sA1[0]), pa1 = __builtin_amdgcn_exp2f(sA1[1]);
        float pa2 = __builtin_amdgcn_exp2f(sA1[2]), pa3 = __builtin_amdgcn_exp2f(sA1[3]);
        float pb0 = __builtin_amdgcn_exp2f(sB1[0]), pb1 = __builtin_amdgcn_exp2f(sB1[1]);
        float pb2 = __builtin_amdgcn_exp2f(sB1[2]), pb3 = __builtin_amdgcn_exp2f(sB1[3]);
        float qa0 = __builtin_amdgcn_exp2f(sA2[0]), qa1 = __builtin_amdgcn_exp2f(sA2[1]);
        float qa2 = __builtin_amdgcn_exp2f(sA2[2]), qa3 = __builtin_amdgcn_exp2f(sA2[3]);
        float qb0 = __builtin_amdgcn_exp2f(sB2[0]), qb1 = __builtin_amdgcn_exp2f(sB2[1]);
        float qb2 = __builtin_amdgcn_exp2f(sB2[2]), qb3 = __builtin_amdgcn_exp2f(sB2[3]);
        l1 += (pa0 + pa1) + (pa2 + pa3) + (pb0 + pb1) + (pb2 + pb3);
        l2 += (qa0 + qa1) + (qa2 + qa3) + (qb0 + qb1) + (qb2 + qb3);
        union { unsigned u[2]; bf16x4 v; } cA1, cB1, cA2, cB2;
        cA1.u[0] = __builtin_amdgcn_perm(__float_as_uint(pa1), __float_as_uint(pa0), 0x07060302u);
        cA1.u[1] = __builtin_amdgcn_perm(__float_as_uint(pa3), __float_as_uint(pa2), 0x07060302u);
        cB1.u[0] = __builtin_amdgcn_perm(__float_as_uint(pb1), __float_as_uint(pb0), 0x07060302u);
        cB1.u[1] = __builtin_amdgcn_perm(__float_as_uint(pb3), __float_as_uint(pb2), 0x07060302u);
        cA2.u[0] = __builtin_amdgcn_perm(__float_as_uint(qa1), __float_as_uint(qa0), 0x07060302u);
        cA2.u[1] = __builtin_amdgcn_perm(__float_as_uint(qa3), __float_as_uint(qa2), 0x07060302u);
        cB2.u[0] = __builtin_amdgcn_perm(__float_as_uint(qb1), __float_as_uint(qb0), 0x07060302u);
        cB2.u[1] = __builtin_amdgcn_perm(__float_as_uint(qb3), __float_as_uint(qb2), 0x07060302u);

        bf16x4 V00 = *(const bf16x4*)(buf + v0o0);
        bf16x4 V10 = *(const bf16x4*)(buf + v1o0);
        bf16x4 V01 = *(const bf16x4*)(buf + v0o1);
        bf16x4 V11 = *(const bf16x4*)(buf + v1o1);

        O1a = __builtin_amdgcn_mfma_f32_16x16x16bf16_1k(cA1.v, V00, O1a, 0, 0, 0);
        O1b = __builtin_amdgcn_mfma_f32_16x16x16bf16_1k(cA1.v, V10, O1b, 0, 0, 0);
        O2a = __builtin_amdgcn_mfma_f32_16x16x16bf16_1k(cA2.v, V00, O2a, 0, 0, 0);
        O2b = __builtin_amdgcn_mfma_f32_16x16x16bf16_1k(cA2.v, V10, O2b, 0, 0, 0);
        O1a = __builtin_amdgcn_mfma_f32_16x16x16bf16_1k(cB1.v, V01, O1a, 0, 0, 0);
        O1b = __builtin_amdgcn_mfma_f32_16x16x16bf16_1k(cB1.v, V11, O1b, 0, 0, 0);
        O2a = __builtin_amdgcn_mfma_f32_16x16x16bf16_1k(cB2.v, V01, O2a, 0, 0, 0);
        O2b = __builtin_amdgcn_mfma_f32_16x16x16bf16_1k(cB2.v, V11, O2b, 0, 0, 0);
    }

    l1 += __shfl_xor(l1, 16, 64); l1 += __shfl_xor(l1, 32, 64);
    l2 += __shfl_xor(l2, 16, 64); l2 += __shfl_xor(l2, 32, 64);
    if (lane < 16) {
        atomicAdd(&lbuf[qtile][0][m], l1);
        atomicAdd(&lbuf[qtile][1][m], l2);
    }
    #pragma unroll
    for (int i = 0; i < 4; ++i) {
        int r = quad * 4 + i;
        atomicAdd(&Obuf[qtile][0][r][m],      O1a[i]);
        atomicAdd(&Obuf[qtile][0][r][16 + m], O1b[i]);
        atomicAdd(&Obuf[qtile][1][r][m],      O2a[i]);
        atomicAdd(&Obuf[qtile][1][r][16 + m], O2b[i]);
    }
    __syncthreads();

    float* dst = parts + (size_t)((h * 128 + qt) * 2 + ks) * PSTRIDE;
    for (int i = t; i < 1024; i += 256) {
        int r = i >> 5, d = i & 31;
        int qtl = r >> 4, rl = r & 15;
        dst[i]        = Obuf[qtl][0][rl][d];
        dst[1024 + i] = Obuf[qtl][1][rl][d];
    }
    if (t < 32) {
        int qtl = t >> 4, rl = t & 15;
        dst[2048 + t] = lbuf[qtl][0][rl];
        dst[2080 + t] = lbuf[qtl][1][rl];
    }
}

// ---------------------------------------------------------------------------
// Kernel 3: split-K merge + finalize (verbatim R11).
// ---------------------------------------------------------------------------
__global__ __launch_bounds__(256) void merge_kernel(
    const float* __restrict__ parts, float* __restrict__ out)
{
    int idx = blockIdx.x * 256 + threadIdx.x;     // 524288
    int row = idx >> 5, d = idx & 31;
    int h = row >> 12, n = row & 4095;
    int qt = n >> 5, r = n & 31;
    const float* p0 = parts + (size_t)((h * 128 + qt) * 2) * PSTRIDE;
    const float* p1 = p0 + PSTRIDE;
    float o1 = p0[r * 32 + d]        + p1[r * 32 + d];
    float o2 = p0[1024 + r * 32 + d] + p1[1024 + r * 32 + d];
    float l1 = p0[2048 + r]          + p1[2048 + r];
    float l2 = p0[2080 + r]          + p1[2080 + r];
    out[idx] = o1 / l1 - LAMBDA_ * o2 / l2;
}

extern "C" void kernel_launch(void* const* d_in, const int* in_sizes, int n_in,
                              void* d_out, int out_size, void* d_ws, size_t ws_size,
                              hipStream_t stream) {
    const float* x = (const float*)d_in[0];   // (1,128,32,32,32)
    const float* w = (const float*)d_in[1];   // (384,128)
    float* out = (float*)d_out;               // [h][n][32] flat (verified R1)

    unsigned short* qA = (unsigned short*)d_ws;               // 2 MB
    unsigned short* kB = qA + (size_t)NH * N_TOK * 64;        // 2 MB
    unsigned short* vT = kB + (size_t)NH * N_TOK * 64;        // 1 MB
    float* parts = (float*)(vT + (size_t)NH * 32 * N_TOK);    // 1024*2112*4B = 8.65 MB
    unsigned short* wh = (unsigned short*)(parts + (size_t)1024 * PSTRIDE); // 96 KB
    unsigned short* wl = wh + 384 * 128;                                    // 96 KB

    prep_w_kernel<<<192, 256, 0, stream>>>(w, wh, wl);
    qkv_kernel<<<512, 256, 0, stream>>>(x, wh, wl, qA, kB, vT);
    flash_kernel<<<1024, 256, 0, stream>>>(qA, kB, vT, parts);
    merge_kernel<<<2048, 256, 0, stream>>>(parts, out);
}